// Round 5
// baseline (225.950 us; speedup 1.0000x reference)
//
#include <hip/hip_runtime.h>

// x [32,64,64,64] f32, emb [64,1024] f32 -> out [ q: 8388608 f32 ][ idx: 131072 f32 ]
// Round 5: same exact split-f16 MFMA math (absmax 0.0 in r3/r4). Changes:
//  - 512-thread blocks, 8 waves = 2 pixel-halves x 4 k-quarters: A-frags 32 regs,
//    best/bestk 16, acc 8 -> ~108 regs/wave, __launch_bounds__(512,4) => 4 waves/SIMD
//  - acc chains start from persistent zero vector (no per-t init), acc in VGPRs
//  - prep widened to 16x256 (was effectively serializing ~60us of bench time)

using half8 = __attribute__((ext_vector_type(8))) _Float16;
using half4 = __attribute__((ext_vector_type(4))) _Float16;
using f32x4 = __attribute__((ext_vector_type(4))) float;

#define XPITCH 72   // halfs per x-row in LDS: 64 + 8 pad

__global__ void prep_kernel(const float* __restrict__ emb,
                            float* __restrict__ e2,
                            _Float16* __restrict__ eTh,
                            _Float16* __restrict__ eTl) {
    const int tx = threadIdx.x;
    const int k  = blockIdx.x * 64 + (tx & 63);   // 16 blocks x 64 ks
    const int cg = tx >> 6;                        // 0..3
#pragma unroll
    for (int cc = 0; cc < 2; ++cc) {
        const int c = cg + cc * 4;                 // 0..7: 8-d group
        half8 hv, lv;
#pragma unroll
        for (int j = 0; j < 8; ++j) {
            float v = emb[(c * 8 + j) * 1024 + k]; // coalesced over k
            _Float16 h = (_Float16)v;
            hv[j] = h;
            lv[j] = (_Float16)(v - (float)h);      // exact residual
        }
        *(half8*)(eTh + k * 64 + c * 8) = hv;
        *(half8*)(eTl + k * 64 + c * 8) = lv;
    }
    if (cg == 0) {                                 // e2: serial ascending-d fmaf,
        float s = 0.f;                             // exact order from round 1
#pragma unroll
        for (int d = 0; d < 64; ++d) {
            float v = emb[d * 1024 + k];
            s = fmaf(v, v, s);
        }
        e2[k] = s;
    }
}

__launch_bounds__(512, 4)
__global__ void vq_kernel(const float* __restrict__ x,
                          const _Float16* __restrict__ eTh,
                          const _Float16* __restrict__ eTl,
                          const float* __restrict__ e2,
                          const float* __restrict__ emb,
                          float* __restrict__ outq,
                          float* __restrict__ outidx) {
    __shared__ _Float16 sxh[64 * XPITCH];
    __shared__ _Float16 sxl[64 * XPITCH];
    __shared__ float rbest[8 * 32];
    __shared__ int   ridx[8 * 32];
    __shared__ int   samin[64];

    const int tx = threadIdx.x;
    const int n0 = blockIdx.x * 64;
    const int bb = n0 >> 12;
    const int hw = n0 & 4095;
    const float* xbase = x + bb * 262144 + hw;

    // ---- stage x -> LDS [p][d] as f16 hi/lo (512 threads, 2 cells each) ----
#pragma unroll
    for (int it = 0; it < 2; ++it) {
        int i  = it * 512 + tx;
        int p  = i & 63;
        int d0 = (i >> 6) << 2;                    // 0,4,...,60
        float v0 = xbase[(d0 + 0) * 4096 + p];     // coalesced over p
        float v1 = xbase[(d0 + 1) * 4096 + p];
        float v2 = xbase[(d0 + 2) * 4096 + p];
        float v3 = xbase[(d0 + 3) * 4096 + p];
        _Float16 h0 = (_Float16)v0, h1 = (_Float16)v1,
                 h2 = (_Float16)v2, h3 = (_Float16)v3;
        half4 hv = {h0, h1, h2, h3};
        half4 lv = {(_Float16)(v0 - (float)h0), (_Float16)(v1 - (float)h1),
                    (_Float16)(v2 - (float)h2), (_Float16)(v3 - (float)h3)};
        *(half4*)(sxh + p * XPITCH + d0) = hv;
        *(half4*)(sxl + p * XPITCH + d0) = lv;
    }
    __syncthreads();

    const int lane = tx & 63;
    const int w    = tx >> 6;       // 0..7
    const int mi   = w >> 2;        // pixel half: 0..1
    const int ki   = w & 3;         // k quarter: 0..3
    const int r16  = lane & 15;
    const int q    = lane >> 4;

    // ---- A-fragments: 32 pixels, loaded once, pinned ----------------------
    half8 ah[2][2], al[2][2];
#pragma unroll
    for (int mt = 0; mt < 2; ++mt)
#pragma unroll
        for (int s = 0; s < 2; ++s) {
            const int px = mi * 32 + mt * 16 + r16;
            ah[mt][s] = *(const half8*)(sxh + px * XPITCH + s * 32 + q * 8);
            al[mt][s] = *(const half8*)(sxl + px * XPITCH + s * 32 + q * 8);
        }
#pragma unroll
    for (int mt = 0; mt < 2; ++mt)
#pragma unroll
        for (int s = 0; s < 2; ++s) {
            asm volatile("" : "+v"(ah[mt][s]));
            asm volatile("" : "+v"(al[mt][s]));
        }

    float best[8];
    int   bestk[8];
#pragma unroll
    for (int i = 0; i < 8; ++i) { best[i] = 3.4e38f; bestk[i] = 0; }

    const f32x4 zero4 = {0.f, 0.f, 0.f, 0.f};      // persistent chain seed

    const int kw = ki << 8;                        // wave's 256-k range
    const _Float16* bhbase = eTh + (kw + r16) * 64 + q * 8;
    const _Float16* blbase = eTl + (kw + r16) * 64 + q * 8;
    const float*    e2base = e2 + kw + r16;

    half8 pbh0, pbh1, pbl0, pbl1; float pe2;
    half8 qbh0, qbh1, qbl0, qbl1; float qe2;

#define LOADSET(BH0, BH1, BL0, BL1, E2V, TT)                                  \
    {                                                                         \
        const int off_ = (TT) << 10;  /* 16 k-rows * 64 halfs */              \
        BH0 = *(const half8*)(bhbase + off_);                                 \
        BH1 = *(const half8*)(bhbase + off_ + 32);                            \
        BL0 = *(const half8*)(blbase + off_);                                 \
        BL1 = *(const half8*)(blbase + off_ + 32);                            \
        E2V = e2base[(TT) << 4];                                              \
    }

#define COMPUTE(BH0, BH1, BL0, BL1, E2V, TT)                                  \
    {                                                                         \
        const int klc_ = kw + ((TT) << 4) + r16;                              \
        _Pragma("unroll")                                                     \
        for (int mt = 0; mt < 2; ++mt) {                                      \
            f32x4 a = zero4;                                                  \
            a = __builtin_amdgcn_mfma_f32_16x16x32_f16(al[mt][0], BL0, a, 0, 0, 0); \
            a = __builtin_amdgcn_mfma_f32_16x16x32_f16(al[mt][1], BL1, a, 0, 0, 0); \
            a = __builtin_amdgcn_mfma_f32_16x16x32_f16(al[mt][0], BH0, a, 0, 0, 0); \
            a = __builtin_amdgcn_mfma_f32_16x16x32_f16(al[mt][1], BH1, a, 0, 0, 0); \
            a = __builtin_amdgcn_mfma_f32_16x16x32_f16(ah[mt][0], BL0, a, 0, 0, 0); \
            a = __builtin_amdgcn_mfma_f32_16x16x32_f16(ah[mt][1], BL1, a, 0, 0, 0); \
            a = __builtin_amdgcn_mfma_f32_16x16x32_f16(ah[mt][0], BH0, a, 0, 0, 0); \
            a = __builtin_amdgcn_mfma_f32_16x16x32_f16(ah[mt][1], BH1, a, 0, 0, 0); \
            _Pragma("unroll")                                                 \
            for (int rr = 0; rr < 4; ++rr) {                                  \
                float dist_ = fmaf(-2.f, a[rr], E2V);                         \
                int i_ = mt * 4 + rr;                                         \
                if (dist_ < best[i_]) { best[i_] = dist_; bestk[i_] = klc_; } \
            }                                                                 \
        }                                                                     \
    }

    LOADSET(pbh0, pbh1, pbl0, pbl1, pe2, 0);
#pragma unroll 1
    for (int t = 0; t < 16; t += 2) {
        LOADSET(qbh0, qbh1, qbl0, qbl1, qe2, t + 1);
        COMPUTE(pbh0, pbh1, pbl0, pbl1, pe2, t);
        LOADSET(pbh0, pbh1, pbl0, pbl1, pe2, (t + 2) & 15);  // wrap load unused at t=14
        COMPUTE(qbh0, qbh1, qbl0, qbl1, qe2, t + 1);
    }

    // ---- per-pixel argmin across the 16 lanes sharing a C-row -------------
#pragma unroll
    for (int i = 0; i < 8; ++i) {
        float bv = best[i];
        int   bk = bestk[i];
#pragma unroll
        for (int m = 1; m < 16; m <<= 1) {
            float ov = __shfl_xor(bv, m, 64);
            int   ok = __shfl_xor(bk, m, 64);
            if (ov < bv || (ov == bv && ok < bk)) { bv = ov; bk = ok; }
        }
        best[i] = bv;
        bestk[i] = bk;
    }
    if (r16 == 0) {
#pragma unroll
        for (int mt = 0; mt < 2; ++mt)
#pragma unroll
            for (int rr = 0; rr < 4; ++rr) {
                int pxl = mt * 16 + q * 4 + rr;    // 0..31 within pixel half
                rbest[w * 32 + pxl] = best[mt * 4 + rr];
                ridx[w * 32 + pxl]  = bestk[mt * 4 + rr];
            }
    }
    __syncthreads();

    // ---- merge the 4 k-quarter waves (ascending ki = ascending k) ---------
    if (tx < 64) {
        const int pmi  = tx >> 5;
        const int pxl  = tx & 31;
        float bv = rbest[(pmi * 4 + 0) * 32 + pxl];
        int   bk = ridx[(pmi * 4 + 0) * 32 + pxl];
#pragma unroll
        for (int g = 1; g < 4; ++g) {
            float v  = rbest[(pmi * 4 + g) * 32 + pxl];
            int   kk = ridx[(pmi * 4 + g) * 32 + pxl];
            if (v < bv || (v == bv && kk < bk)) { bv = v; bk = kk; }
        }
        samin[tx] = bk;
        outidx[n0 + tx] = (float)bk;
    }
    __syncthreads();

    // ---- gather exact fp32 codebook rows -> output ------------------------
    const int p = tx & 63;
    const int drow = tx >> 6;                      // 0..7
    const int amin = samin[p];
    float* obase = outq + bb * 262144 + hw + p;
#pragma unroll
    for (int it = 0; it < 8; ++it) {
        int d = it * 8 + drow;
        obase[d * 4096] = emb[d * 1024 + amin];
    }
}

extern "C" void kernel_launch(void* const* d_in, const int* in_sizes, int n_in,
                              void* d_out, int out_size, void* d_ws, size_t ws_size,
                              hipStream_t stream) {
    const float* x   = (const float*)d_in[0];
    const float* emb = (const float*)d_in[1];
    float* outq   = (float*)d_out;
    float* outidx = outq + 8388608;

    float*    e2  = (float*)d_ws;                               // 4 KB
    _Float16* eTh = (_Float16*)((char*)d_ws + 4096);            // 128 KB
    _Float16* eTl = (_Float16*)((char*)d_ws + 4096 + 131072);   // 128 KB

    prep_kernel<<<16, 256, 0, stream>>>(emb, e2, eTh, eTl);
    vq_kernel<<<2048, 512, 0, stream>>>(x, eTh, eTl, e2, emb, outq, outidx);
}

// Round 9
// 165.972 us; speedup vs baseline: 1.3614x; 1.3614x over previous
//
#include <hip/hip_runtime.h>

// x [32,64,64,64] f32, emb [64,1024] f32 -> out [ q: 8388608 f32 ][ idx: 131072 f32 ]
// Round 9: A/B infra diagnostic after 3 container failures on the r6 pipeline
// kernel. This is EXACTLY the round-4 vq_kernel (ran: 101.5 us, absmax 0.0)
// plus the round-5 prep_kernel (ran in r5). No new constructs. If this fails
// too, the broker is down; if it passes, r6's macro pipeline was the trigger.

using half8 = __attribute__((ext_vector_type(8))) _Float16;
using half4 = __attribute__((ext_vector_type(4))) _Float16;
using f32x4 = __attribute__((ext_vector_type(4))) float;

#define XPITCH 72   // halfs per x-row in LDS: 64 + 8 pad

__global__ void prep_kernel(const float* __restrict__ emb,
                            float* __restrict__ e2,
                            _Float16* __restrict__ eTh,
                            _Float16* __restrict__ eTl) {
    const int tx = threadIdx.x;
    const int k  = blockIdx.x * 64 + (tx & 63);   // 16 blocks x 64 ks
    const int cg = tx >> 6;                        // 0..3
#pragma unroll
    for (int cc = 0; cc < 2; ++cc) {
        const int c = cg + cc * 4;                 // 8-d group
        half8 hv, lv;
#pragma unroll
        for (int j = 0; j < 8; ++j) {
            float v = emb[(c * 8 + j) * 1024 + k]; // coalesced over k
            _Float16 h = (_Float16)v;
            hv[j] = h;
            lv[j] = (_Float16)(v - (float)h);      // exact residual
        }
        *(half8*)(eTh + k * 64 + c * 8) = hv;
        *(half8*)(eTl + k * 64 + c * 8) = lv;
    }
    if (cg == 0) {                                 // e2: serial ascending-d fmaf
        float s = 0.f;
#pragma unroll
        for (int d = 0; d < 64; ++d) {
            float v = emb[d * 1024 + k];
            s = fmaf(v, v, s);
        }
        e2[k] = s;
    }
}

__launch_bounds__(256)
__global__ void vq_kernel(const float* __restrict__ x,
                          const _Float16* __restrict__ eTh,
                          const _Float16* __restrict__ eTl,
                          const float* __restrict__ e2,
                          const float* __restrict__ emb,
                          float* __restrict__ outq,
                          float* __restrict__ outidx) {
    __shared__ _Float16 sxh[64 * XPITCH];
    __shared__ _Float16 sxl[64 * XPITCH];
    __shared__ float rbest[256];
    __shared__ int   ridx[256];
    __shared__ int   samin[64];

    const int tx = threadIdx.x;
    const int n0 = blockIdx.x * 64;
    const int bb = n0 >> 12;
    const int hw = n0 & 4095;
    const float* xbase = x + bb * 262144 + hw;

    // ---- stage x -> LDS [p][d] as f16 hi/lo --------------------------------
    {
        const int p  = tx & 63;
        const int dg = (tx >> 6) << 2;
#pragma unroll
        for (int it = 0; it < 4; ++it) {
            int d0 = it * 16 + dg;
            float v0 = xbase[(d0 + 0) * 4096 + p];
            float v1 = xbase[(d0 + 1) * 4096 + p];
            float v2 = xbase[(d0 + 2) * 4096 + p];
            float v3 = xbase[(d0 + 3) * 4096 + p];
            _Float16 h0 = (_Float16)v0, h1 = (_Float16)v1,
                     h2 = (_Float16)v2, h3 = (_Float16)v3;
            half4 hv = {h0, h1, h2, h3};
            half4 lv = {(_Float16)(v0 - (float)h0), (_Float16)(v1 - (float)h1),
                        (_Float16)(v2 - (float)h2), (_Float16)(v3 - (float)h3)};
            *(half4*)(sxh + p * XPITCH + d0) = hv;
            *(half4*)(sxl + p * XPITCH + d0) = lv;
        }
    }
    __syncthreads();

    const int lane = tx & 63;
    const int w    = tx >> 6;
    const int r16  = lane & 15;
    const int q    = lane >> 4;

    // ---- A-fragments, loaded once, pinned ----------------------------------
    half8 ah[4][2], al[4][2];
#pragma unroll
    for (int mt = 0; mt < 4; ++mt)
#pragma unroll
        for (int s = 0; s < 2; ++s) {
            ah[mt][s] = *(const half8*)(sxh + (mt * 16 + r16) * XPITCH + s * 32 + q * 8);
            al[mt][s] = *(const half8*)(sxl + (mt * 16 + r16) * XPITCH + s * 32 + q * 8);
        }
#pragma unroll
    for (int mt = 0; mt < 4; ++mt)
#pragma unroll
        for (int s = 0; s < 2; ++s) {
            asm volatile("" : "+v"(ah[mt][s]));   // forbid LDS remat in loop
            asm volatile("" : "+v"(al[mt][s]));
        }

    float best[16];
    int   bestk[16];
#pragma unroll
    for (int i = 0; i < 16; ++i) { best[i] = 3.4e38f; bestk[i] = 0; }

    const int kw = w << 8;
    const _Float16* bhbase = eTh + (kw + r16) * 64 + q * 8;
    const _Float16* blbase = eTl + (kw + r16) * 64 + q * 8;
    const float*    e2base = e2 + kw + r16;

    half8 pbh0, pbh1, pbl0, pbl1; float pe2;
    half8 qbh0, qbh1, qbl0, qbl1; float qe2;

#define LOADSET(BH0, BH1, BL0, BL1, E2V, TT)                                  \
    {                                                                         \
        const int off_ = (TT) << 10;  /* 16 k-rows * 64 halfs */              \
        BH0 = *(const half8*)(bhbase + off_);                                 \
        BH1 = *(const half8*)(bhbase + off_ + 32);                            \
        BL0 = *(const half8*)(blbase + off_);                                 \
        BL1 = *(const half8*)(blbase + off_ + 32);                            \
        E2V = e2base[(TT) << 4];                                              \
    }

#define COMPUTE(BH0, BH1, BL0, BL1, E2V, TT)                                  \
    {                                                                         \
        const int klc_ = kw + ((TT) << 4) + r16;                              \
        _Pragma("unroll")                                                     \
        for (int mt = 0; mt < 4; ++mt) {                                      \
            f32x4 a = {0.f, 0.f, 0.f, 0.f};                                   \
            a = __builtin_amdgcn_mfma_f32_16x16x32_f16(al[mt][0], BL0, a, 0, 0, 0); \
            a = __builtin_amdgcn_mfma_f32_16x16x32_f16(al[mt][1], BL1, a, 0, 0, 0); \
            a = __builtin_amdgcn_mfma_f32_16x16x32_f16(al[mt][0], BH0, a, 0, 0, 0); \
            a = __builtin_amdgcn_mfma_f32_16x16x32_f16(al[mt][1], BH1, a, 0, 0, 0); \
            a = __builtin_amdgcn_mfma_f32_16x16x32_f16(ah[mt][0], BL0, a, 0, 0, 0); \
            a = __builtin_amdgcn_mfma_f32_16x16x32_f16(ah[mt][1], BL1, a, 0, 0, 0); \
            a = __builtin_amdgcn_mfma_f32_16x16x32_f16(ah[mt][0], BH0, a, 0, 0, 0); \
            a = __builtin_amdgcn_mfma_f32_16x16x32_f16(ah[mt][1], BH1, a, 0, 0, 0); \
            _Pragma("unroll")                                                 \
            for (int rr = 0; rr < 4; ++rr) {                                  \
                float dist_ = fmaf(-2.f, a[rr], E2V);                         \
                int i_ = mt * 4 + rr;                                         \
                if (dist_ < best[i_]) { best[i_] = dist_; bestk[i_] = klc_; } \
            }                                                                 \
        }                                                                     \
    }

    LOADSET(pbh0, pbh1, pbl0, pbl1, pe2, 0);
#pragma unroll 1
    for (int t = 0; t < 16; t += 2) {
        LOADSET(qbh0, qbh1, qbl0, qbl1, qe2, t + 1);
        COMPUTE(pbh0, pbh1, pbl0, pbl1, pe2, t);
        LOADSET(pbh0, pbh1, pbl0, pbl1, pe2, (t + 2) & 15);  // wrap load unused at t=14
        COMPUTE(qbh0, qbh1, qbl0, qbl1, qe2, t + 1);
    }

    // ---- per-pixel argmin across the 16 lanes sharing a C-row --------------
#pragma unroll
    for (int i = 0; i < 16; ++i) {
        float bv = best[i];
        int   bk = bestk[i];
#pragma unroll
        for (int m = 1; m < 16; m <<= 1) {
            float ov = __shfl_xor(bv, m, 64);
            int   ok = __shfl_xor(bk, m, 64);
            if (ov < bv || (ov == bv && ok < bk)) { bv = ov; bk = ok; }
        }
        best[i] = bv;
        bestk[i] = bk;
    }
    if (r16 == 0) {
#pragma unroll
        for (int mt = 0; mt < 4; ++mt)
#pragma unroll
            for (int rr = 0; rr < 4; ++rr) {
                int p = mt * 16 + q * 4 + rr;
                rbest[w * 64 + p] = best[mt * 4 + rr];
                ridx[w * 64 + p]  = bestk[mt * 4 + rr];
            }
    }
    __syncthreads();

    // ---- cross-wave merge (ascending wave = ascending k) -------------------
    if (tx < 64) {
        float bv = rbest[tx];
        int   bk = ridx[tx];
#pragma unroll
        for (int g = 1; g < 4; ++g) {
            float v  = rbest[g * 64 + tx];
            int   kk = ridx[g * 64 + tx];
            if (v < bv || (v == bv && kk < bk)) { bv = v; bk = kk; }
        }
        samin[tx] = bk;
        outidx[n0 + tx] = (float)bk;
    }
    __syncthreads();

    // ---- gather exact fp32 codebook rows -> output -------------------------
    const int p = tx & 63;
    const int drow = tx >> 6;
    const int amin = samin[p];
    float* obase = outq + bb * 262144 + hw + p;
#pragma unroll
    for (int it = 0; it < 16; ++it) {
        int d = (it << 2) + drow;
        obase[d * 4096] = emb[d * 1024 + amin];
    }
}

extern "C" void kernel_launch(void* const* d_in, const int* in_sizes, int n_in,
                              void* d_out, int out_size, void* d_ws, size_t ws_size,
                              hipStream_t stream) {
    const float* x   = (const float*)d_in[0];
    const float* emb = (const float*)d_in[1];
    float* outq   = (float*)d_out;
    float* outidx = outq + 8388608;

    float*    e2  = (float*)d_ws;                               // 4 KB
    _Float16* eTh = (_Float16*)((char*)d_ws + 4096);            // 128 KB
    _Float16* eTl = (_Float16*)((char*)d_ws + 4096 + 131072);   // 128 KB

    prep_kernel<<<16, 256, 0, stream>>>(emb, e2, eTh, eTl);
    vq_kernel<<<2048, 256, 0, stream>>>(x, eTh, eTl, e2, emb, outq, outidx);
}